// Round 4
// baseline (358.997 us; speedup 1.0000x reference)
//
#include <hip/hip_runtime.h>
#include <hip/hip_bf16.h>
#include <math.h>

// bf16 stored as short (raw bits); fp32 accumulate in MFMA.
using bf16x8 = __attribute__((ext_vector_type(8))) short;
using f32x4  = __attribute__((ext_vector_type(4))) float;
using f32x16 = __attribute__((ext_vector_type(16))) float;
using i32x4  = __attribute__((ext_vector_type(4))) int;
using i32x2  = __attribute__((ext_vector_type(2))) int;

#define MFMA_BF16(a, b, c) __builtin_amdgcn_mfma_f32_16x16x32_bf16((a), (b), (c), 0, 0, 0)
#define MFMA32(a, b, c)    __builtin_amdgcn_mfma_f32_32x32x16_bf16((a), (b), (c), 0, 0, 0)

__device__ __forceinline__ float bf2f(short s) {
    union { unsigned u; float f; } v;
    v.u = ((unsigned)(unsigned short)s) << 16;
    return v.f;
}
__device__ __forceinline__ short f2bf(float f) {
    union { float f; unsigned u; } v; v.f = f;
    unsigned r = v.u + 0x7FFF + ((v.u >> 16) & 1);  // round-to-nearest-even
    return (short)(r >> 16);
}
// Native packed f32->bf16 convert (RNE), 1 VALU op for 2 values.
__device__ __forceinline__ int cvtpk_bf16(float lo, float hi) {
    int r;
    asm("v_cvt_pk_bf16_f32 %0, %1, %2" : "=v"(r) : "v"(lo), "v"(hi));
    return r;
}
// v_permlane32_swap_b32: a'[l<32]=a[l], a'[32+i]=b[i]; b'[i]=a[32+i], b'[32+i]=b[32+i].
__device__ __forceinline__ void permswap(int &a, int &b) {
#if __has_builtin(__builtin_amdgcn_permlane32_swap)
    typedef unsigned u32x2v __attribute__((ext_vector_type(2)));
    u32x2v r = __builtin_amdgcn_permlane32_swap((unsigned)a, (unsigned)b, false, false);
    a = (int)r[0]; b = (int)r[1];
#else
    asm volatile("v_permlane32_swap_b32 %0, %1" : "+v"(a), "+v"(b));
#endif
}
// Raw 2^x (v_exp_f32). Q is pre-scaled by log2(e)/8 so this IS exp(score).
__device__ __forceinline__ float fexp2(float x) {
#if __has_builtin(__builtin_amdgcn_exp2f)
    return __builtin_amdgcn_exp2f(x);
#else
    return exp2f(x);
#endif
}

// Async global->LDS DMA, 16B per lane (LDS dest = wave base + lane*16).
__device__ __forceinline__ void gload_lds16(const void* g, void* l) {
    __builtin_amdgcn_global_load_lds(
        (const __attribute__((address_space(1))) void*)g,
        (__attribute__((address_space(3))) void*)l, 16, 0, 0);
}

// ---------------------------------------------------------------------------
// Input dtype detector (proven R3). flag: 1=bf16, 0=fp32.
// ---------------------------------------------------------------------------
__global__ void detect_dtype(const unsigned short* __restrict__ emb, int* flag) {
    __shared__ int tot;
    if (threadIdx.x == 0) tot = 0;
    __syncthreads();
    int c = 0;
    for (int i = 0; i < 64; i++) {
        unsigned short v = emb[2 * (threadIdx.x * 64 + i)];
        unsigned e = (v >> 7) & 0xFF;
        if (v == 0 || v == 0x8000u || (e >= 97 && e <= 137)) c++;
    }
    atomicAdd(&tot, c);
    __syncthreads();
    if (threadIdx.x == 0) *flag = (tot > 8192) ? 1 : 0;
}

__global__ void convert8(const void* __restrict__ src, short* __restrict__ dst,
                         int n8, const int* __restrict__ flag) {
    int i = blockIdx.x * 256 + threadIdx.x;
    if (i >= n8) return;
    if (*flag) {
        ((bf16x8*)dst)[i] = ((const bf16x8*)src)[i];
    } else {
        const float* f = (const float*)src + (size_t)i * 8;
        bf16x8 o;
#pragma unroll
        for (int j = 0; j < 8; j++) o[j] = f2bf(f[j]);
        ((bf16x8*)dst)[i] = o;
    }
}

// All 4 weights (131072 n8 each) + 4 biases (128 n8 each) in ONE launch.
// Grid = 2050 blocks x 256 = 524800 = 4*131072 + 4*128 exactly.
__global__ void convert_all(
    const void* __restrict__ w0, const void* __restrict__ w1,
    const void* __restrict__ w2, const void* __restrict__ w3,
    const void* __restrict__ b0, const void* __restrict__ b1,
    const void* __restrict__ b2, const void* __restrict__ b3,
    short* dw0, short* dw1, short* dw2, short* dw3,
    short* db0, short* db1, short* db2, short* db3,
    const int* __restrict__ flag)
{
    int i = blockIdx.x * 256 + threadIdx.x;
    const void* src; short* dst; int idx;
    if (i < 524288) {
        int w = i >> 17; idx = i & 131071;
        src = (w == 0) ? w0 : (w == 1) ? w1 : (w == 2) ? w2 : w3;
        dst = (w == 0) ? dw0 : (w == 1) ? dw1 : (w == 2) ? dw2 : dw3;
    } else {
        int j = i - 524288; int b = j >> 7; idx = j & 127;
        src = (b == 0) ? b0 : (b == 1) ? b1 : (b == 2) ? b2 : b3;
        dst = (b == 0) ? db0 : (b == 1) ? db1 : (b == 2) ? db2 : db3;
    }
    if (*flag) {
        ((bf16x8*)dst)[idx] = ((const bf16x8*)src)[idx];
    } else {
        const float* f = (const float*)src + (size_t)idx * 8;
        bf16x8 o;
#pragma unroll
        for (int j = 0; j < 8; j++) o[j] = f2bf(f[j]);
        ((bf16x8*)dst)[idx] = o;
    }
}

// ---------------------------------------------------------------------------
// GEMM R12: R11 + vectorized mode-1 (Vt) epilogue.
//  - XCD swizzle: swz=(bid&7)*64+(bid>>3) -> each XCD owns 8 m-panels
//    (2 MB A, L2-resident) x all n.
//  - Double-buffered LDS + counted s_waitcnt vmcnt(4) + raw barriers.
//  - LDS XOR chunk swizzle (both sides): LDS row r chunk c holds global
//    chunk c^((r>>1)&3); fragment reads chunk = quad^((lr>>1)&3).
//  - mode 1 epilogue: 4 consecutive rows per (i,j) packed via cvt_pk into
//    one 8B store (16 stores/thread instead of 64 2B stores). Same RNE bits.
// mode: 0 = bf16 natural, 1 = bf16 transposed (Vt), 2 = per *flag dtype.
// ---------------------------------------------------------------------------
__global__ __launch_bounds__(256) void gemm128(
    const short* __restrict__ A,
    const short* __restrict__ B0, const short* __restrict__ B1,
    const short* __restrict__ B2,
    const short* __restrict__ bias0, const short* __restrict__ bias1,
    const short* __restrict__ bias2,
    void* __restrict__ C0, void* __restrict__ C1, void* __restrict__ C2,
    float s0, float s1, float s2,
    int mode0, int mode1, int mode2,
    const int* __restrict__ flag)
{
    constexpr int M = 8192, N = 1024, Kd = 1024, BK = 32;
    __shared__ __align__(16) short As[2][128 * BK];
    __shared__ __align__(16) short Bs[2][128 * BK];

    const int z = blockIdx.z;
    const short* B    = (z == 0) ? B0    : (z == 1) ? B1    : B2;
    const short* bias = (z == 0) ? bias0 : (z == 1) ? bias1 : bias2;
    void*  C     = (z == 0) ? C0 : (z == 1) ? C1 : C2;
    float  scale = (z == 0) ? s0 : (z == 1) ? s1 : s2;
    int    mode  = (z == 0) ? mode0 : (z == 1) ? mode1 : mode2;

    const int tid  = threadIdx.x;
    const int lane = tid & 63;
    const int wave = tid >> 6;
    const int lr   = lane & 15;
    const int quad = lane >> 4;

    // XCD-aware bijective swizzle (512 blocks, 8 XCDs; XCD = bid%8).
    const int bid = blockIdx.x;
    const int swz = ((bid & 7) << 6) | (bid >> 3);
    const int m0 = (swz >> 3) * 128;
    const int n0 = (swz & 7) * 128;
    const int wm = (wave >> 1) * 64;
    const int wn = (wave & 1) * 64;

    // staging: lane covers row lane>>2, chunk lane&3; source chunk XOR-swizzled
    const int srow = lane >> 2;
    const int scol = (((lane & 3) ^ ((lane >> 3) & 3)) * 8);
    // fragment read chunk (shorts offset): quad ^ ((lr>>1)&3)
    const int rchunk = (quad ^ ((lr >> 1) & 3)) * 8;

    int fl = 1;
    if (mode == 2) fl = *flag;

    f32x4 acc[4][4];
#pragma unroll
    for (int i = 0; i < 4; i++)
#pragma unroll
        for (int j = 0; j < 4; j++) acc[i][j] = (f32x4){0.f, 0.f, 0.f, 0.f};

    auto stage = [&](int bufi, int k) {
#pragma unroll
        for (int t = 0; t < 2; t++) {
            const int r = wave * 32 + t * 16;
            gload_lds16(A + (size_t)(m0 + r + srow) * Kd + k + scol,
                        &As[bufi][r * BK]);
            gload_lds16(B + (size_t)(n0 + r + srow) * Kd + k + scol,
                        &Bs[bufi][r * BK]);
        }
    };

    stage(0, 0);
    for (int k0 = 0; k0 < Kd; k0 += BK) {
        const int cur = (k0 >> 5) & 1;
        stage(cur ^ 1, (k0 + BK) & (Kd - 1));   // last iter wraps: harmless
        asm volatile("s_waitcnt vmcnt(4)" ::: "memory");  // tile cur complete
        __builtin_amdgcn_s_barrier();
        __builtin_amdgcn_sched_barrier(0);

        bf16x8 a[4], b[4];
#pragma unroll
        for (int i = 0; i < 4; i++)
            a[i] = *(const bf16x8*)(&As[cur][(wm + i * 16 + lr) * BK + rchunk]);
#pragma unroll
        for (int j = 0; j < 4; j++)
            b[j] = *(const bf16x8*)(&Bs[cur][(wn + j * 16 + lr) * BK + rchunk]);
#pragma unroll
        for (int i = 0; i < 4; i++)
#pragma unroll
            for (int j = 0; j < 4; j++)
                acc[i][j] = MFMA_BF16(a[i], b[j], acc[i][j]);

        asm volatile("s_waitcnt lgkmcnt(0)" ::: "memory");
        __builtin_amdgcn_sched_barrier(0);
        __builtin_amdgcn_s_barrier();
    }

    if (mode == 1) {
        // Vt: C[col][row], 4 consecutive rows per (i,j) -> one 8B store.
#pragma unroll
        for (int j = 0; j < 4; j++) {
            const int col = n0 + wn + j * 16 + lr;
            const float bv = bf2f(bias[col]);
#pragma unroll
            for (int i = 0; i < 4; i++) {
                const int row = m0 + wm + i * 16 + quad * 4;
                const float v0 = (acc[i][j][0] + bv) * scale;
                const float v1 = (acc[i][j][1] + bv) * scale;
                const float v2 = (acc[i][j][2] + bv) * scale;
                const float v3 = (acc[i][j][3] + bv) * scale;
                i32x2 dd;
                dd[0] = cvtpk_bf16(v0, v1);
                dd[1] = cvtpk_bf16(v2, v3);
                *(i32x2*)((short*)C + (size_t)col * M + row) = dd;
            }
        }
    } else {
#pragma unroll
        for (int j = 0; j < 4; j++) {
            const int col = n0 + wn + j * 16 + lr;
            const float bv = bf2f(bias[col]);
#pragma unroll
            for (int i = 0; i < 4; i++) {
#pragma unroll
                for (int r = 0; r < 4; r++) {
                    const int row = m0 + wm + i * 16 + quad * 4 + r;
                    const float v = (acc[i][j][r] + bv) * scale;
                    if (mode == 0) ((short*)C)[(size_t)row * N + col] = f2bf(v);
                    else {
                        if (fl) ((short*)C)[(size_t)row * N + col] = f2bf(v);
                        else    ((float*)C)[(size_t)row * N + col] = v;
                    }
                }
            }
        }
    }
}

// ---------------------------------------------------------------------------
// Flash attention R12: R10 structure + bank-conflict fix + MFMA row-sum.
//  - Fragment reads: row*128B never changes bank (128B = full 32-bank wrap),
//    so lanes {x,x+8,x+16,x+24} (same l31&7, same chunk) were 4-way
//    conflicted. Fix: fold ((row>>3)&3) into the XOR on BOTH sides:
//      LDS row r chunk c holds global chunk c ^ (r&7) ^ ((r>>3)&3)
//    stage source chunk = (l&7)^(l>>3)^t; read chunk = base ^ xr where
//    xr = (l31&7) ^ ((l31>>3)&3). Every 8-lane group covers all 8 chunks.
//  - Row-sum via ones-MFMA: l_acc = MFMA32(pf, ones, l_acc). B=ones =>
//    D[q][j] = sum_kv P[q][kv] for all j, so l_acc[r] = l[qrow(r)] in-lane.
//    Removes 33 serial VALU adds/tile AND the 18-shuffle epilogue reduce;
//    moves the work to the 29%-utilized matrix pipe.
// S^T = mfma(K, Q): lane holds P[q=lane&31][kv subset] lane-locally.
// Aout may alias Q: each wave reads only the 32 Q rows it alone writes.
// ---------------------------------------------------------------------------
__global__ __launch_bounds__(256, 4) void attn_kernel(
    const short* Q, const short* __restrict__ K,
    const short* __restrict__ Vt, short* Aout)
{
    // [buf][0]=K tile [kv 0..63][64 c], [buf][1]=V tile [d 0..63][64 kv]
    __shared__ __align__(16) short lds[2][2][64][64];   // 32 KiB

    const int tid  = threadIdx.x;
    const int lane = tid & 63;
    const int wave = tid >> 6;
    const int l31  = lane & 31;
    const int hi   = lane >> 5;
    const int xr   = (l31 & 7) ^ ((l31 >> 3) & 3);   // read-side XOR

    const int qt = blockIdx.x;
    const int bh = blockIdx.y;
    const int b  = bh >> 4, h = bh & 15;
    const int q0 = b * 2048 + qt * 128 + wave * 32;
    const int c0 = h * 64;

    // staging geometry: lane l -> row r0+(l>>3), LDS chunk l&7;
    // source chunk = (l&7) ^ (l>>3) ^ t  (t = (r0>>3)&3 of the 8-row group)
    const int sr  = lane >> 3;
    const int scb = (lane & 7) ^ sr;
    const int sarr = wave >> 1;                // waves 0,1 -> K; 2,3 -> V

    const short* Kb = K  + (size_t)(b * 2048) * 1024 + c0;
    const short* Vb = Vt + (size_t)c0 * 8192 + b * 2048;

    // Q as B-fragments: lane holds Q[q=l31][c = slot*16 + hi*8 + 0..7]
    bf16x8 qf[4];
#pragma unroll
    for (int slot = 0; slot < 4; slot++)
        qf[slot] = *(const bf16x8*)(Q + (size_t)(q0 + l31) * 1024 + c0 + slot * 16 + hi * 8);

    auto stage = [&](int bufi, int kt) {
#pragma unroll
        for (int t = 0; t < 4; t++) {
            const int r0 = ((wave & 1) * 4 + t) * 8;
            const int sc = (scb ^ t) * 8;
            short* dst = &lds[bufi][sarr][r0][0];       // wave-uniform base
            if (sarr == 0)
                gload_lds16(Kb + (size_t)(kt + r0 + sr) * 1024 + sc, dst);
            else
                gload_lds16(Vb + (size_t)(r0 + sr) * 8192 + kt + sc, dst);
        }
    };

    bf16x8 onesf;
#pragma unroll
    for (int j = 0; j < 8; j++) onesf[j] = (short)0x3F80;   // bf16 1.0

    f32x16 o[2], l_acc;
#pragma unroll
    for (int r = 0; r < 16; r++) { o[0][r] = 0.f; o[1][r] = 0.f; l_acc[r] = 0.f; }

    stage(0, 0);
    for (int kt = 0; kt < 2048; kt += 64) {
        const int cur = (kt >> 6) & 1;
        stage(cur ^ 1, (kt + 64) & 2047);   // last iter wraps: harmless re-stage
        asm volatile("s_waitcnt vmcnt(4)" ::: "memory");  // tile cur complete
        __builtin_amdgcn_s_barrier();
        __builtin_amdgcn_sched_barrier(0);

        // S^T[kv][q]: st[blk] covers kv = blk*32 + crow(reg,hi), q = l31
        f32x16 st[2];
#pragma unroll
        for (int blk = 0; blk < 2; blk++) {
#pragma unroll
            for (int r = 0; r < 16; r++) st[blk][r] = 0.f;
#pragma unroll
            for (int slot = 0; slot < 4; slot++) {
                bf16x8 kf = *(const bf16x8*)
                    &lds[cur][0][blk * 32 + l31][(((slot << 1) | hi) ^ xr) * 8];
                st[blk] = MFMA32(kf, qf[slot], st[blk]);
            }
        }

        // exp (log2-domain scores); row-sum now via ones-MFMA below
#pragma unroll
        for (int blk = 0; blk < 2; blk++)
#pragma unroll
            for (int r = 0; r < 16; r++)
                st[blk][r] = fexp2(st[blk][r]);

        // P -> A-fragments (cvt_pk + permlane32_swap) fused with PV MFMAs
#pragma unroll
        for (int ks = 0; ks < 4; ks++) {
            const int blk = ks >> 1;
            const int rb  = (ks & 1) * 8;
            int A0 = cvtpk_bf16(st[blk][rb + 0], st[blk][rb + 1]);
            int A1 = cvtpk_bf16(st[blk][rb + 2], st[blk][rb + 3]);
            int B0 = cvtpk_bf16(st[blk][rb + 4], st[blk][rb + 5]);
            int B1 = cvtpk_bf16(st[blk][rb + 6], st[blk][rb + 7]);
            permswap(A0, B0);   // A0 -> dw0 (j0,j1), B0 -> dw2 (j4,j5)
            permswap(A1, B1);   // A1 -> dw1 (j2,j3), B1 -> dw3 (j6,j7)
            i32x4 paw; paw[0] = A0; paw[1] = A1; paw[2] = B0; paw[3] = B1;
            const bf16x8 pf = *(const bf16x8*)&paw;
            l_acc = MFMA32(pf, onesf, l_acc);   // row-sum on matrix pipe
#pragma unroll
            for (int dblk = 0; dblk < 2; dblk++) {
                bf16x8 vf = *(const bf16x8*)
                    &lds[cur][1][dblk * 32 + l31][(((ks << 1) | hi) ^ xr) * 8];
                o[dblk] = MFMA32(pf, vf, o[dblk]);
            }
        }

        asm volatile("s_waitcnt lgkmcnt(0)" ::: "memory");
        __builtin_amdgcn_sched_barrier(0);
        __builtin_amdgcn_s_barrier();
    }

    // l_acc[r] = l[qrow(r)] already in-lane: no cross-lane reduce needed.
#pragma unroll
    for (int r = 0; r < 16; r++) {
        const int qrow = (r & 3) + 8 * (r >> 2) + 4 * hi;
        const float inv = 1.f / l_acc[r];
#pragma unroll
        for (int dblk = 0; dblk < 2; dblk++)
            Aout[(size_t)(q0 + qrow) * 1024 + c0 + dblk * 32 + l31] =
                f2bf(o[dblk][r] * inv);
    }
}

// ---------------------------------------------------------------------------
extern "C" void kernel_launch(void* const* d_in, const int* in_sizes, int n_in,
                              void* d_out, int out_size, void* d_ws, size_t ws_size,
                              hipStream_t stream)
{
    const size_t MB = (size_t)1024 * 1024;
    char* ws = (char*)d_ws;

    int*   flagp = (int*)ws;                 // [0, 256)
    short* embC  = (short*)(ws + 1 * MB);    // 16 MB [8192][1024]
    short* wC[4] = { (short*)(ws + 17 * MB), (short*)(ws + 19 * MB),
                     (short*)(ws + 21 * MB), (short*)(ws + 23 * MB) };  // 2 MB ea
    short* bC[4] = { (short*)(ws + 25 * MB), (short*)(ws + 25 * MB + 4096),
                     (short*)(ws + 25 * MB + 8192), (short*)(ws + 25 * MB + 12288) };

    short *Qb, *Kb, *Vt, *Ab;
    if (ws_size >= 90 * MB) {
        Qb = (short*)(ws + 26 * MB);
        Kb = (short*)(ws + 42 * MB);
        Vt = (short*)(ws + 58 * MB);
        Ab = (short*)(ws + 74 * MB);
    } else {
        Qb = (short*)(ws + 26 * MB);
        Kb = (short*)d_out;      // dead after attention; final GEMM rewrites
        Vt = (short*)(ws + 42 * MB);
        Ab = Qb;                 // alias: safe per attn_kernel note
    }

    detect_dtype<<<1, 256, 0, stream>>>((const unsigned short*)d_in[0], flagp);

    convert8<<<4096, 256, 0, stream>>>(d_in[0], embC, 1048576, flagp);   // emb
    convert_all<<<2050, 256, 0, stream>>>(
        d_in[1], d_in[3], d_in[5], d_in[7],
        d_in[2], d_in[4], d_in[6], d_in[8],
        wC[0], wC[1], wC[2], wC[3],
        bC[0], bC[1], bC[2], bC[3], flagp);

    dim3 blk(256);
    // Fused QKV; Q scale = log2(e)/8 (log2-domain softmax, see attn header).
    gemm128<<<dim3(512, 1, 3), blk, 0, stream>>>(
        embC, wC[0], wC[1], wC[2], bC[0], bC[1], bC[2],
        Qb, Kb, Vt, 0.18033688011112042f, 1.0f, 1.0f, 0, 0, 1, nullptr);

    attn_kernel<<<dim3(16, 64), blk, 0, stream>>>(Qb, Kb, Vt, Ab);

    gemm128<<<dim3(512, 1, 1), blk, 0, stream>>>(
        Ab, wC[3], nullptr, nullptr, bC[3], nullptr, nullptr,
        d_out, nullptr, nullptr, 1.0f, 0.f, 0.f, 2, 0, 0, flagp);
}

// Round 5
// 311.612 us; speedup vs baseline: 1.1521x; 1.1521x over previous
//
#include <hip/hip_runtime.h>
#include <hip/hip_bf16.h>
#include <math.h>

// bf16 stored as short (raw bits); fp32 accumulate in MFMA.
using bf16x8 = __attribute__((ext_vector_type(8))) short;
using f32x4  = __attribute__((ext_vector_type(4))) float;
using f32x16 = __attribute__((ext_vector_type(16))) float;
using i32x4  = __attribute__((ext_vector_type(4))) int;
using i32x2  = __attribute__((ext_vector_type(2))) int;

#define MFMA_BF16(a, b, c) __builtin_amdgcn_mfma_f32_16x16x32_bf16((a), (b), (c), 0, 0, 0)
#define MFMA32(a, b, c)    __builtin_amdgcn_mfma_f32_32x32x16_bf16((a), (b), (c), 0, 0, 0)

__device__ __forceinline__ float bf2f(short s) {
    union { unsigned u; float f; } v;
    v.u = ((unsigned)(unsigned short)s) << 16;
    return v.f;
}
__device__ __forceinline__ short f2bf(float f) {
    union { float f; unsigned u; } v; v.f = f;
    unsigned r = v.u + 0x7FFF + ((v.u >> 16) & 1);  // round-to-nearest-even
    return (short)(r >> 16);
}
// Native packed f32->bf16 convert (RNE), 1 VALU op for 2 values.
__device__ __forceinline__ int cvtpk_bf16(float lo, float hi) {
    int r;
    asm("v_cvt_pk_bf16_f32 %0, %1, %2" : "=v"(r) : "v"(lo), "v"(hi));
    return r;
}
// v_permlane32_swap_b32: a'[l<32]=a[l], a'[32+i]=b[i]; b'[i]=a[32+i], b'[32+i]=b[32+i].
__device__ __forceinline__ void permswap(int &a, int &b) {
#if __has_builtin(__builtin_amdgcn_permlane32_swap)
    typedef unsigned u32x2v __attribute__((ext_vector_type(2)));
    u32x2v r = __builtin_amdgcn_permlane32_swap((unsigned)a, (unsigned)b, false, false);
    a = (int)r[0]; b = (int)r[1];
#else
    asm volatile("v_permlane32_swap_b32 %0, %1" : "+v"(a), "+v"(b));
#endif
}
// Raw 2^x (v_exp_f32). Q is pre-scaled by log2(e)/8 so this IS exp(score).
__device__ __forceinline__ float fexp2(float x) {
#if __has_builtin(__builtin_amdgcn_exp2f)
    return __builtin_amdgcn_exp2f(x);
#else
    return exp2f(x);
#endif
}

// Async global->LDS DMA, 16B per lane (LDS dest = wave base + lane*16).
__device__ __forceinline__ void gload_lds16(const void* g, void* l) {
    __builtin_amdgcn_global_load_lds(
        (const __attribute__((address_space(1))) void*)g,
        (__attribute__((address_space(3))) void*)l, 16, 0, 0);
}

// ---------------------------------------------------------------------------
// Input dtype detector (proven R3). flag: 1=bf16, 0=fp32.
// ---------------------------------------------------------------------------
__global__ void detect_dtype(const unsigned short* __restrict__ emb, int* flag) {
    __shared__ int tot;
    if (threadIdx.x == 0) tot = 0;
    __syncthreads();
    int c = 0;
    for (int i = 0; i < 64; i++) {
        unsigned short v = emb[2 * (threadIdx.x * 64 + i)];
        unsigned e = (v >> 7) & 0xFF;
        if (v == 0 || v == 0x8000u || (e >= 97 && e <= 137)) c++;
    }
    atomicAdd(&tot, c);
    __syncthreads();
    if (threadIdx.x == 0) *flag = (tot > 8192) ? 1 : 0;
}

__global__ void convert8(const void* __restrict__ src, short* __restrict__ dst,
                         int n8, const int* __restrict__ flag) {
    int i = blockIdx.x * 256 + threadIdx.x;
    if (i >= n8) return;
    if (*flag) {
        ((bf16x8*)dst)[i] = ((const bf16x8*)src)[i];
    } else {
        const float* f = (const float*)src + (size_t)i * 8;
        bf16x8 o;
#pragma unroll
        for (int j = 0; j < 8; j++) o[j] = f2bf(f[j]);
        ((bf16x8*)dst)[i] = o;
    }
}

// All 4 weights (131072 n8 each) + 4 biases (128 n8 each) in ONE launch.
// Grid = 2050 blocks x 256 = 524800 = 4*131072 + 4*128 exactly.
__global__ void convert_all(
    const void* __restrict__ w0, const void* __restrict__ w1,
    const void* __restrict__ w2, const void* __restrict__ w3,
    const void* __restrict__ b0, const void* __restrict__ b1,
    const void* __restrict__ b2, const void* __restrict__ b3,
    short* dw0, short* dw1, short* dw2, short* dw3,
    short* db0, short* db1, short* db2, short* db3,
    const int* __restrict__ flag)
{
    int i = blockIdx.x * 256 + threadIdx.x;
    const void* src; short* dst; int idx;
    if (i < 524288) {
        int w = i >> 17; idx = i & 131071;
        src = (w == 0) ? w0 : (w == 1) ? w1 : (w == 2) ? w2 : w3;
        dst = (w == 0) ? dw0 : (w == 1) ? dw1 : (w == 2) ? dw2 : dw3;
    } else {
        int j = i - 524288; int b = j >> 7; idx = j & 127;
        src = (b == 0) ? b0 : (b == 1) ? b1 : (b == 2) ? b2 : b3;
        dst = (b == 0) ? db0 : (b == 1) ? db1 : (b == 2) ? db2 : db3;
    }
    if (*flag) {
        ((bf16x8*)dst)[idx] = ((const bf16x8*)src)[idx];
    } else {
        const float* f = (const float*)src + (size_t)idx * 8;
        bf16x8 o;
#pragma unroll
        for (int j = 0; j < 8; j++) o[j] = f2bf(f[j]);
        ((bf16x8*)dst)[idx] = o;
    }
}

// ---------------------------------------------------------------------------
// GEMM R12 (unchanged): m97 structure + XCD swizzle + dbuf/counted-vmcnt +
// LDS XOR chunk swizzle + vectorized mode-1 epilogue.
// mode: 0 = bf16 natural, 1 = bf16 transposed (Vt), 2 = per *flag dtype.
// ---------------------------------------------------------------------------
__global__ __launch_bounds__(256) void gemm128(
    const short* __restrict__ A,
    const short* __restrict__ B0, const short* __restrict__ B1,
    const short* __restrict__ B2,
    const short* __restrict__ bias0, const short* __restrict__ bias1,
    const short* __restrict__ bias2,
    void* __restrict__ C0, void* __restrict__ C1, void* __restrict__ C2,
    float s0, float s1, float s2,
    int mode0, int mode1, int mode2,
    const int* __restrict__ flag)
{
    constexpr int M = 8192, N = 1024, Kd = 1024, BK = 32;
    __shared__ __align__(16) short As[2][128 * BK];
    __shared__ __align__(16) short Bs[2][128 * BK];

    const int z = blockIdx.z;
    const short* B    = (z == 0) ? B0    : (z == 1) ? B1    : B2;
    const short* bias = (z == 0) ? bias0 : (z == 1) ? bias1 : bias2;
    void*  C     = (z == 0) ? C0 : (z == 1) ? C1 : C2;
    float  scale = (z == 0) ? s0 : (z == 1) ? s1 : s2;
    int    mode  = (z == 0) ? mode0 : (z == 1) ? mode1 : mode2;

    const int tid  = threadIdx.x;
    const int lane = tid & 63;
    const int wave = tid >> 6;
    const int lr   = lane & 15;
    const int quad = lane >> 4;

    // XCD-aware bijective swizzle (512 blocks, 8 XCDs; XCD = bid%8).
    const int bid = blockIdx.x;
    const int swz = ((bid & 7) << 6) | (bid >> 3);
    const int m0 = (swz >> 3) * 128;
    const int n0 = (swz & 7) * 128;
    const int wm = (wave >> 1) * 64;
    const int wn = (wave & 1) * 64;

    // staging: lane covers row lane>>2, chunk lane&3; source chunk XOR-swizzled
    const int srow = lane >> 2;
    const int scol = (((lane & 3) ^ ((lane >> 3) & 3)) * 8);
    // fragment read chunk (shorts offset): quad ^ ((lr>>1)&3)
    const int rchunk = (quad ^ ((lr >> 1) & 3)) * 8;

    int fl = 1;
    if (mode == 2) fl = *flag;

    f32x4 acc[4][4];
#pragma unroll
    for (int i = 0; i < 4; i++)
#pragma unroll
        for (int j = 0; j < 4; j++) acc[i][j] = (f32x4){0.f, 0.f, 0.f, 0.f};

    auto stage = [&](int bufi, int k) {
#pragma unroll
        for (int t = 0; t < 2; t++) {
            const int r = wave * 32 + t * 16;
            gload_lds16(A + (size_t)(m0 + r + srow) * Kd + k + scol,
                        &As[bufi][r * BK]);
            gload_lds16(B + (size_t)(n0 + r + srow) * Kd + k + scol,
                        &Bs[bufi][r * BK]);
        }
    };

    stage(0, 0);
    for (int k0 = 0; k0 < Kd; k0 += BK) {
        const int cur = (k0 >> 5) & 1;
        stage(cur ^ 1, (k0 + BK) & (Kd - 1));   // last iter wraps: harmless
        asm volatile("s_waitcnt vmcnt(4)" ::: "memory");  // tile cur complete
        __builtin_amdgcn_s_barrier();
        __builtin_amdgcn_sched_barrier(0);

        bf16x8 a[4], b[4];
#pragma unroll
        for (int i = 0; i < 4; i++)
            a[i] = *(const bf16x8*)(&As[cur][(wm + i * 16 + lr) * BK + rchunk]);
#pragma unroll
        for (int j = 0; j < 4; j++)
            b[j] = *(const bf16x8*)(&Bs[cur][(wn + j * 16 + lr) * BK + rchunk]);
#pragma unroll
        for (int i = 0; i < 4; i++)
#pragma unroll
            for (int j = 0; j < 4; j++)
                acc[i][j] = MFMA_BF16(a[i], b[j], acc[i][j]);

        asm volatile("s_waitcnt lgkmcnt(0)" ::: "memory");
        __builtin_amdgcn_sched_barrier(0);
        __builtin_amdgcn_s_barrier();
    }

    if (mode == 1) {
        // Vt: C[col][row], 4 consecutive rows per (i,j) -> one 8B store.
#pragma unroll
        for (int j = 0; j < 4; j++) {
            const int col = n0 + wn + j * 16 + lr;
            const float bv = bf2f(bias[col]);
#pragma unroll
            for (int i = 0; i < 4; i++) {
                const int row = m0 + wm + i * 16 + quad * 4;
                const float v0 = (acc[i][j][0] + bv) * scale;
                const float v1 = (acc[i][j][1] + bv) * scale;
                const float v2 = (acc[i][j][2] + bv) * scale;
                const float v3 = (acc[i][j][3] + bv) * scale;
                i32x2 dd;
                dd[0] = cvtpk_bf16(v0, v1);
                dd[1] = cvtpk_bf16(v2, v3);
                *(i32x2*)((short*)C + (size_t)col * M + row) = dd;
            }
        }
    } else {
#pragma unroll
        for (int j = 0; j < 4; j++) {
            const int col = n0 + wn + j * 16 + lr;
            const float bv = bf2f(bias[col]);
#pragma unroll
            for (int i = 0; i < 4; i++) {
#pragma unroll
                for (int r = 0; r < 4; r++) {
                    const int row = m0 + wm + i * 16 + quad * 4 + r;
                    const float v = (acc[i][j][r] + bv) * scale;
                    if (mode == 0) ((short*)C)[(size_t)row * N + col] = f2bf(v);
                    else {
                        if (fl) ((short*)C)[(size_t)row * N + col] = f2bf(v);
                        else    ((float*)C)[(size_t)row * N + col] = v;
                    }
                }
            }
        }
    }
}

// ---------------------------------------------------------------------------
// Flash attention R13: R12 minus the spill-inducing launch_bounds.
//  - __launch_bounds__(256) ONLY: R4's (256,4) capped VGPRs at 64 while live
//    state needs ~115 -> accumulator spills to scratch (WRITE_SIZE 16->37MB,
//    +50us). Compiler-chosen occupancy (~2 blocks/CU, as in the 102us R2/R3
//    runs) with zero spills is strictly better here.
//  - Bank-conflict fix (VERIFIED R4: SQ_LDS_BANK_CONFLICT 8.4e6 -> 0):
//    row*128B wraps all 32 banks, so XOR must fold BOTH (r&7) and ((r>>3)&3):
//      LDS row r chunk c holds global chunk c ^ (r&7) ^ ((r>>3)&3)
//    stage source chunk = (l&7)^(l>>3)^t; read chunk ^= (l31&7)^((l31>>3)&3).
//  - Row-sum via ones-MFMA: l_acc = MFMA32(pf, ones, l_acc); l_acc[r] is
//    l[qrow(r)] in-lane (no epilogue cross-lane reduce), 33 VALU adds/tile
//    moved to the matrix pipe.
// S^T = mfma(K, Q): lane holds P[q=lane&31][kv subset] lane-locally.
// Aout may alias Q: each wave reads only the 32 Q rows it alone writes.
// ---------------------------------------------------------------------------
__global__ __launch_bounds__(256) void attn_kernel(
    const short* Q, const short* __restrict__ K,
    const short* __restrict__ Vt, short* Aout)
{
    // [buf][0]=K tile [kv 0..63][64 c], [buf][1]=V tile [d 0..63][64 kv]
    __shared__ __align__(16) short lds[2][2][64][64];   // 32 KiB

    const int tid  = threadIdx.x;
    const int lane = tid & 63;
    const int wave = tid >> 6;
    const int l31  = lane & 31;
    const int hi   = lane >> 5;
    const int xr   = (l31 & 7) ^ ((l31 >> 3) & 3);   // read-side XOR

    const int qt = blockIdx.x;
    const int bh = blockIdx.y;
    const int b  = bh >> 4, h = bh & 15;
    const int q0 = b * 2048 + qt * 128 + wave * 32;
    const int c0 = h * 64;

    // staging geometry: lane l -> row r0+(l>>3), LDS chunk l&7;
    // source chunk = (l&7) ^ (l>>3) ^ t  (t = (r0>>3)&3 of the 8-row group)
    const int sr  = lane >> 3;
    const int scb = (lane & 7) ^ sr;
    const int sarr = wave >> 1;                // waves 0,1 -> K; 2,3 -> V

    const short* Kb = K  + (size_t)(b * 2048) * 1024 + c0;
    const short* Vb = Vt + (size_t)c0 * 8192 + b * 2048;

    // Q as B-fragments: lane holds Q[q=l31][c = slot*16 + hi*8 + 0..7]
    bf16x8 qf[4];
#pragma unroll
    for (int slot = 0; slot < 4; slot++)
        qf[slot] = *(const bf16x8*)(Q + (size_t)(q0 + l31) * 1024 + c0 + slot * 16 + hi * 8);

    auto stage = [&](int bufi, int kt) {
#pragma unroll
        for (int t = 0; t < 4; t++) {
            const int r0 = ((wave & 1) * 4 + t) * 8;
            const int sc = (scb ^ t) * 8;
            short* dst = &lds[bufi][sarr][r0][0];       // wave-uniform base
            if (sarr == 0)
                gload_lds16(Kb + (size_t)(kt + r0 + sr) * 1024 + sc, dst);
            else
                gload_lds16(Vb + (size_t)(r0 + sr) * 8192 + kt + sc, dst);
        }
    };

    bf16x8 onesf;
#pragma unroll
    for (int j = 0; j < 8; j++) onesf[j] = (short)0x3F80;   // bf16 1.0

    f32x16 o[2], l_acc;
#pragma unroll
    for (int r = 0; r < 16; r++) { o[0][r] = 0.f; o[1][r] = 0.f; l_acc[r] = 0.f; }

    stage(0, 0);
    for (int kt = 0; kt < 2048; kt += 64) {
        const int cur = (kt >> 6) & 1;
        stage(cur ^ 1, (kt + 64) & 2047);   // last iter wraps: harmless re-stage
        asm volatile("s_waitcnt vmcnt(4)" ::: "memory");  // tile cur complete
        __builtin_amdgcn_s_barrier();
        __builtin_amdgcn_sched_barrier(0);

        // S^T[kv][q]: st[blk] covers kv = blk*32 + crow(reg,hi), q = l31
        f32x16 st[2];
#pragma unroll
        for (int blk = 0; blk < 2; blk++) {
#pragma unroll
            for (int r = 0; r < 16; r++) st[blk][r] = 0.f;
#pragma unroll
            for (int slot = 0; slot < 4; slot++) {
                bf16x8 kf = *(const bf16x8*)
                    &lds[cur][0][blk * 32 + l31][(((slot << 1) | hi) ^ xr) * 8];
                st[blk] = MFMA32(kf, qf[slot], st[blk]);
            }
        }

        // exp (log2-domain scores); row-sum via ones-MFMA below
#pragma unroll
        for (int blk = 0; blk < 2; blk++)
#pragma unroll
            for (int r = 0; r < 16; r++)
                st[blk][r] = fexp2(st[blk][r]);

        // P -> A-fragments (cvt_pk + permlane32_swap) fused with PV MFMAs
#pragma unroll
        for (int ks = 0; ks < 4; ks++) {
            const int blk = ks >> 1;
            const int rb  = (ks & 1) * 8;
            int A0 = cvtpk_bf16(st[blk][rb + 0], st[blk][rb + 1]);
            int A1 = cvtpk_bf16(st[blk][rb + 2], st[blk][rb + 3]);
            int B0 = cvtpk_bf16(st[blk][rb + 4], st[blk][rb + 5]);
            int B1 = cvtpk_bf16(st[blk][rb + 6], st[blk][rb + 7]);
            permswap(A0, B0);   // A0 -> dw0 (j0,j1), B0 -> dw2 (j4,j5)
            permswap(A1, B1);   // A1 -> dw1 (j2,j3), B1 -> dw3 (j6,j7)
            i32x4 paw; paw[0] = A0; paw[1] = A1; paw[2] = B0; paw[3] = B1;
            const bf16x8 pf = *(const bf16x8*)&paw;
            l_acc = MFMA32(pf, onesf, l_acc);   // row-sum on matrix pipe
#pragma unroll
            for (int dblk = 0; dblk < 2; dblk++) {
                bf16x8 vf = *(const bf16x8*)
                    &lds[cur][1][dblk * 32 + l31][(((ks << 1) | hi) ^ xr) * 8];
                o[dblk] = MFMA32(pf, vf, o[dblk]);
            }
        }

        asm volatile("s_waitcnt lgkmcnt(0)" ::: "memory");
        __builtin_amdgcn_sched_barrier(0);
        __builtin_amdgcn_s_barrier();
    }

    // l_acc[r] = l[qrow(r)] already in-lane: no cross-lane reduce needed.
#pragma unroll
    for (int r = 0; r < 16; r++) {
        const int qrow = (r & 3) + 8 * (r >> 2) + 4 * hi;
        const float inv = 1.f / l_acc[r];
#pragma unroll
        for (int dblk = 0; dblk < 2; dblk++)
            Aout[(size_t)(q0 + qrow) * 1024 + c0 + dblk * 32 + l31] =
                f2bf(o[dblk][r] * inv);
    }
}

// ---------------------------------------------------------------------------
extern "C" void kernel_launch(void* const* d_in, const int* in_sizes, int n_in,
                              void* d_out, int out_size, void* d_ws, size_t ws_size,
                              hipStream_t stream)
{
    const size_t MB = (size_t)1024 * 1024;
    char* ws = (char*)d_ws;

    int*   flagp = (int*)ws;                 // [0, 256)
    short* embC  = (short*)(ws + 1 * MB);    // 16 MB [8192][1024]
    short* wC[4] = { (short*)(ws + 17 * MB), (short*)(ws + 19 * MB),
                     (short*)(ws + 21 * MB), (short*)(ws + 23 * MB) };  // 2 MB ea
    short* bC[4] = { (short*)(ws + 25 * MB), (short*)(ws + 25 * MB + 4096),
                     (short*)(ws + 25 * MB + 8192), (short*)(ws + 25 * MB + 12288) };

    short *Qb, *Kb, *Vt, *Ab;
    if (ws_size >= 90 * MB) {
        Qb = (short*)(ws + 26 * MB);
        Kb = (short*)(ws + 42 * MB);
        Vt = (short*)(ws + 58 * MB);
        Ab = (short*)(ws + 74 * MB);
    } else {
        Qb = (short*)(ws + 26 * MB);
        Kb = (short*)d_out;      // dead after attention; final GEMM rewrites
        Vt = (short*)(ws + 42 * MB);
        Ab = Qb;                 // alias: safe per attn_kernel note
    }

    detect_dtype<<<1, 256, 0, stream>>>((const unsigned short*)d_in[0], flagp);

    convert8<<<4096, 256, 0, stream>>>(d_in[0], embC, 1048576, flagp);   // emb
    convert_all<<<2050, 256, 0, stream>>>(
        d_in[1], d_in[3], d_in[5], d_in[7],
        d_in[2], d_in[4], d_in[6], d_in[8],
        wC[0], wC[1], wC[2], wC[3],
        bC[0], bC[1], bC[2], bC[3], flagp);

    dim3 blk(256);
    // Fused QKV; Q scale = log2(e)/8 (log2-domain softmax, see attn header).
    gemm128<<<dim3(512, 1, 3), blk, 0, stream>>>(
        embC, wC[0], wC[1], wC[2], bC[0], bC[1], bC[2],
        Qb, Kb, Vt, 0.18033688011112042f, 1.0f, 1.0f, 0, 0, 1, nullptr);

    attn_kernel<<<dim3(16, 64), blk, 0, stream>>>(Qb, Kb, Vt, Ab);

    gemm128<<<dim3(512, 1, 1), blk, 0, stream>>>(
        Ab, wC[3], nullptr, nullptr, bC[3], nullptr, nullptr,
        d_out, nullptr, nullptr, 1.0f, 0.f, 0.f, 2, 0, 0, flagp);
}